// Round 17
// baseline (474.414 us; speedup 1.0000x reference)
//
#include <hip/hip_runtime.h>
#include <math.h>

// dims: B=8, DM=256, H=W=32, L=HW=1024, R=4, DI=512, DH=256, N=16, K=4, DTR=16

typedef _Float16 half8 __attribute__((ext_vector_type(8)));
typedef float f4 __attribute__((ext_vector_type(4)));

__device__ __forceinline__ int srcmap(int r, int l) {
  int i = l >> 5, j = l & 31;
  int h, w;
  if (r == 0)      { h = i;      w = j;      }
  else if (r == 1) { h = j;      w = 31 - i; }
  else if (r == 2) { h = 31 - i; w = 31 - j; }
  else             { h = 31 - j; w = i;      }
  return (h << 5) + w;
}

__device__ __forceinline__ float siluf(float x)    { return x / (1.f + __expf(-x)); }
__device__ __forceinline__ float sigmoidf_(float x){ return 1.f / (1.f + __expf(-x)); }
__device__ __forceinline__ float geluf(float x) {
  float x3 = x * x * x;
  return 0.5f * x * (1.f + tanhf(0.7978845608028654f * (x + 0.044715f * x3)));
}

// ---------------- prep (merged): inw split, gwH/opH casts, cavg zero, sa_w1 pack ----------------
__global__ void k_prep(const float* __restrict__ inw, const float* __restrict__ gw,
                       const float* __restrict__ opw, const float* __restrict__ saw1,
                       _Float16* __restrict__ inwH, _Float16* __restrict__ inwL,
                       _Float16* __restrict__ gwH, _Float16* __restrict__ opH,
                       float* __restrict__ cavg, _Float16* __restrict__ Whg2) {
  int idx = blockIdx.x * 256 + threadIdx.x;
  if (idx < 131072) {
    float v = inw[idx];
    _Float16 h = (_Float16)v;
    inwH[idx] = h;
    inwL[idx] = (_Float16)(v - (float)h);
  } else if (idx < 655360) {
    int i = idx - 131072;
    gwH[i] = (_Float16)gw[i];
  } else if (idx < 786432) {
    int i = idx - 655360;
    opH[i] = (_Float16)opw[i];
  } else if (idx < 802816) {
    cavg[idx - 786432] = 0.f;
  } else if (idx < 3162112) {
    int o = idx - 802816;            // < 2,359,296
    int ci = o & 2047;
    int co = (o >> 11) & 127;
    int tap = o >> 18;
    size_t dst = (((size_t)(tap * 64 + (ci >> 5)) * 128) + co) * 32 + (ci & 31);
    Whg2[dst] = (_Float16)saw1[((size_t)co * 2048 + ci) * 9 + tap];
  }
}

// ---------------- x -> pix-major fp16 hi/lo pair: xTh/xTl[b][pix][c] ----------------
__global__ void __launch_bounds__(256) k_xT(const float* __restrict__ x,
                                            _Float16* __restrict__ xTh,
                                            _Float16* __restrict__ xTl) {
  __shared__ float t[32][132];
  int p0 = blockIdx.x * 128, c0 = blockIdx.y * 32, b = blockIdx.z;
  const float* src = x + ((size_t)(b * 256 + c0)) * 1024 + p0;
#pragma unroll
  for (int i = 0; i < 16; ++i) {
    int idx = threadIdx.x + i * 256;
    int ci = idx >> 7, pp = idx & 127;
    t[ci][pp] = src[(size_t)ci * 1024 + pp];
  }
  __syncthreads();
  int pp = threadIdx.x >> 1;
  int ch = (threadIdx.x & 1) * 16;
  _Float16 bh[16], bl[16];
#pragma unroll
  for (int j = 0; j < 16; ++j) {
    float f = t[ch + j][pp];
    _Float16 h = (_Float16)f;
    bh[j] = h;
    bl[j] = (_Float16)(f - (float)h);
  }
  size_t o = ((size_t)(b * 1024) + p0 + pp) * 256 + c0 + ch;
  *(half8*)(xTh + o)     = *(half8*)bh;
  *(half8*)(xTh + o + 8) = *(half8*)(bh + 8);
  *(half8*)(xTl + o)     = *(half8*)bl;
  *(half8*)(xTl + o + 8) = *(half8*)(bl + 8);
}

// ---------------- in_proj via split-fp16 MFMA (fp32-accurate): xz[b][d][pix] ----------------
__global__ void __launch_bounds__(256) k_inprojmfma(const _Float16* __restrict__ xTh,
                                                    const _Float16* __restrict__ xTl,
                                                    const _Float16* __restrict__ inwH,
                                                    const _Float16* __restrict__ inwL,
                                                    float* __restrict__ xz) {
  int wid = threadIdx.x >> 6, lane = threadIdx.x & 63;
  int r = lane & 15, g = lane >> 4;
  int m0 = blockIdx.x * 128 + (wid >> 1) * 64;   // d
  int n0 = blockIdx.y * 128 + (wid & 1) * 64;    // pix
  int b  = blockIdx.z;
  f4 acc[4][4];
#pragma unroll
  for (int mi = 0; mi < 4; ++mi)
#pragma unroll
    for (int ni = 0; ni < 4; ++ni) acc[mi][ni] = (f4){0.f, 0.f, 0.f, 0.f};
  for (int kk = 0; kk < 256; kk += 32) {
    half8 ah[4], al[4], bh[4], bl[4];
#pragma unroll
    for (int mi = 0; mi < 4; ++mi) {
      size_t o = (size_t)(m0 + mi * 16 + r) * 256 + kk + g * 8;
      ah[mi] = *(const half8*)(inwH + o);
      al[mi] = *(const half8*)(inwL + o);
    }
#pragma unroll
    for (int ni = 0; ni < 4; ++ni) {
      size_t o = ((size_t)(b * 1024) + n0 + ni * 16 + r) * 256 + kk + g * 8;
      bh[ni] = *(const half8*)(xTh + o);
      bl[ni] = *(const half8*)(xTl + o);
    }
#pragma unroll
    for (int mi = 0; mi < 4; ++mi)
#pragma unroll
      for (int ni = 0; ni < 4; ++ni) {
        acc[mi][ni] = __builtin_amdgcn_mfma_f32_16x16x32_f16(ah[mi], bh[ni], acc[mi][ni], 0, 0, 0);
        acc[mi][ni] = __builtin_amdgcn_mfma_f32_16x16x32_f16(ah[mi], bl[ni], acc[mi][ni], 0, 0, 0);
        acc[mi][ni] = __builtin_amdgcn_mfma_f32_16x16x32_f16(al[mi], bh[ni], acc[mi][ni], 0, 0, 0);
      }
  }
#pragma unroll
  for (int mi = 0; mi < 4; ++mi)
#pragma unroll
    for (int ni = 0; ni < 4; ++ni) {
      int pix = n0 + ni * 16 + r;
#pragma unroll
      for (int j = 0; j < 4; ++j) {
        int d = m0 + mi * 16 + g * 4 + j;
        xz[((size_t)(b * 512) + d) * 1024 + pix] = acc[mi][ni][j];
      }
    }
}

// ---------------- merged depthwise conv1d + SiLU (x- and z-halves), LDS-tiled ----------------
__global__ void __launch_bounds__(256) k_conv(const float* __restrict__ xz,
                                              const float* __restrict__ cxw,
                                              const float* __restrict__ cxb,
                                              const float* __restrict__ czw,
                                              const float* __restrict__ czb,
                                              float* __restrict__ xseq,
                                              float* __restrict__ Y) {
  int d = blockIdx.x;   // 0..255
  int b = blockIdx.y;   // 0..7
  __shared__ float xs_t[1024];
  __shared__ float zs_t[1024];
  int t4 = threadIdx.x * 4;
  *(float4*)&xs_t[t4] = *(const float4*)(xz + ((size_t)(b * 512 + d)) * 1024 + t4);
  *(float4*)&zs_t[t4] = *(const float4*)(xz + ((size_t)(b * 512 + 256 + d)) * 1024 + t4);
  __syncthreads();
#pragma unroll
  for (int r = 0; r < 4; ++r) {
    int rd = r * 256 + d;
    float xw0 = cxw[rd*4+0], xw1 = cxw[rd*4+1], xw2 = cxw[rd*4+2], xw3 = cxw[rd*4+3];
    float zw0 = czw[rd*4+0], zw1 = czw[rd*4+1], zw2 = czw[rd*4+2], zw3 = czw[rd*4+3];
    float xbi = cxb[rd], zbi = czb[rd];
    float xo[4], zo[4];
#pragma unroll
    for (int q = 0; q < 4; ++q) {
      int l = t4 + q;
      float ax = xbi, az = zbi;
      if (l - 1 >= 0) {
        int s = srcmap(r, l - 1);
        ax = fmaf(xw0, xs_t[s], ax); az = fmaf(zw0, zs_t[s], az);
      }
      {
        int s = srcmap(r, l);
        ax = fmaf(xw1, xs_t[s], ax); az = fmaf(zw1, zs_t[s], az);
      }
      if (l + 1 < 1024) {
        int s = srcmap(r, l + 1);
        ax = fmaf(xw2, xs_t[s], ax); az = fmaf(zw2, zs_t[s], az);
      }
      if (l + 2 < 1024) {
        int s = srcmap(r, l + 2);
        ax = fmaf(xw3, xs_t[s], ax); az = fmaf(zw3, zs_t[s], az);
      }
      xo[q] = siluf(ax); zo[q] = siluf(az);
    }
    *(float4*)(xseq + ((size_t)(b * 4 + r) * 256 + d) * 1024 + t4) = *(float4*)xo;
    *(float4*)(Y + ((size_t)(b * 4 + r) * 512 + 256 + d) * 1024 + t4) = *(float4*)zo;
  }
}

// ---------------- x_dbl v2: LDS-staged x-tile, f4 weight loads; xdT[br][ch][32c][48k] ----------------
__global__ void __launch_bounds__(256) k_xdblT(const float* __restrict__ xseq,
                                               const float* __restrict__ xpw,
                                               float* __restrict__ xdT) {
  int ch = blockIdx.x;          // 0..31
  int br = blockIdx.y;          // 0..31
  int r  = br & 3;
  __shared__ float xs_t[256][33];
  const float* base = xseq + (size_t)(br * 256) * 1024 + ch * 32;
  {
    int c4 = threadIdx.x & 7;
    int drow = threadIdx.x >> 3;
#pragma unroll
    for (int p = 0; p < 8; ++p) {
      int dd = p * 32 + drow;
      float4 v = *(const float4*)(base + (size_t)dd * 1024 + c4 * 4);
      xs_t[dd][c4*4+0] = v.x; xs_t[dd][c4*4+1] = v.y;
      xs_t[dd][c4*4+2] = v.z; xs_t[dd][c4*4+3] = v.w;
    }
  }
  __syncthreads();
  int c  = threadIdx.x & 31;
  int kq = threadIdx.x >> 5;    // 0..7, 6 k each
  const float* w = xpw + (r * 48 + kq * 6) * 256;
  float acc[6] = {0.f, 0.f, 0.f, 0.f, 0.f, 0.f};
  for (int d0 = 0; d0 < 256; d0 += 4) {
    float x0 = xs_t[d0][c], x1 = xs_t[d0+1][c], x2 = xs_t[d0+2][c], x3 = xs_t[d0+3][c];
#pragma unroll
    for (int j = 0; j < 6; ++j) {
      float4 wv = *(const float4*)(w + j * 256 + d0);
      acc[j] = fmaf(wv.x, x0, fmaf(wv.y, x1, fmaf(wv.z, x2, fmaf(wv.w, x3, acc[j]))));
    }
  }
  float* o = xdT + ((size_t)(br * 32 + ch) * 32 + c) * 48 + kq * 6;
#pragma unroll
  for (int j = 0; j < 6; ++j) o[j] = acc[j];
}

// ---------------- chunked selective scan (chunk=32) ----------------
// Pass A: chunk-local end-state (h0=0); stores spsum and packed fp16 sp (compact coalesced)
__global__ void __launch_bounds__(256) k_scanA(
    const float* __restrict__ xseq, const float* __restrict__ xdT,
    const float* __restrict__ dtw_, const float* __restrict__ dtb_,
    const float* __restrict__ alogs,
    float* __restrict__ spsum_g, _Float16* __restrict__ sp16,
    float* __restrict__ Yc) {
  int ch = blockIdx.x;
  int br = blockIdx.y; int r = br & 3;
  int d  = threadIdx.x;
  int rd = r * 256 + d;
  f4 w0 = *(const f4*)&dtw_[rd * 16], w1 = *(const f4*)&dtw_[rd * 16 + 4],
     w2 = *(const f4*)&dtw_[rd * 16 + 8], w3 = *(const f4*)&dtw_[rd * 16 + 12];
  float A2[16], h[16];
#pragma unroll
  for (int n = 0; n < 16; ++n) A2[n] = -__expf(alogs[rd * 16 + n]) * 1.44269504f;
#pragma unroll
  for (int n = 0; n < 16; ++n) h[n] = 0.f;
  float spsum = 0.f;
  float bias = dtb_[rd];
  half8 sph[4];
  __shared__ __align__(16) float t2[1536];
  const float* xd = xdT + (size_t)(br * 32 + ch) * 1536;
  {
    int i = threadIdx.x;        // 256 f4 units: c = i>>3, k4 = i&7 (k in [0,32))
    int c = i >> 3, k4 = i & 7;
    ((f4*)t2)[c * 12 + k4] = ((const f4*)xd)[c * 12 + k4];
  }
  __syncthreads();
  const float* us = xseq + (size_t)(br * 256 + d) * 1024 + ch * 32;
#pragma unroll
  for (int c4 = 0; c4 < 8; ++c4) {
    float4 uv = *(const float4*)(us + c4 * 4);
    float uarr[4] = {uv.x, uv.y, uv.z, uv.w};
#pragma unroll
    for (int cc = 0; cc < 4; ++cc) {
      const f4* row = (const f4*)&t2[(c4 * 4 + cc) * 48];
      f4 td0 = row[0], td1 = row[1], td2 = row[2], td3 = row[3];
      float delta = bias
        + td0[0]*w0[0] + td0[1]*w0[1] + td0[2]*w0[2] + td0[3]*w0[3]
        + td1[0]*w1[0] + td1[1]*w1[1] + td1[2]*w1[2] + td1[3]*w1[3]
        + td2[0]*w2[0] + td2[1]*w2[1] + td2[2]*w2[2] + td2[3]*w2[3]
        + td3[0]*w3[0] + td3[1]*w3[1] + td3[2]*w3[2] + td3[3]*w3[3];
      float sp = (delta > 20.f) ? delta : __logf(1.f + __expf(delta));
      sph[c4 >> 1][(c4 & 1) * 4 + cc] = (_Float16)sp;
      float du = sp * uarr[cc];
      spsum += sp;
      f4 tb[4] = {row[4], row[5], row[6], row[7]};
#pragma unroll
      for (int n = 0; n < 16; ++n) {
        float e = exp2f(sp * A2[n]);
        h[n] = fmaf(e, h[n], du * tb[n >> 2][n & 3]);
      }
    }
  }
  spsum_g[((size_t)br * 32 + ch) * 256 + d] = spsum;
  _Float16* spo = sp16 + (((size_t)(br * 32 + ch)) * 256 + d) * 32;
  *(f4*)(spo)      = *(f4*)&sph[0];
  *(f4*)(spo + 8)  = *(f4*)&sph[1];
  *(f4*)(spo + 16) = *(f4*)&sph[2];
  *(f4*)(spo + 24) = *(f4*)&sph[3];
  float* hco = Yc + (size_t)(br * 512 + d) * 1024 + ch * 32;
#pragma unroll
  for (int n = 0; n < 16; ++n) hco[n] = h[n];
}

// Pass B: prefix over chunks; aprod recomputed from spsum
__global__ void k_scanB(const float* __restrict__ spsum_g, const float* __restrict__ alogs,
                        float* __restrict__ Yc) {
  int t  = blockIdx.x * 256 + threadIdx.x;   // br*4096 + d*16 + n
  int br = t >> 12;
  int dn = t & 4095;
  int d = dn >> 4, n = dn & 15;
  int r = br & 3;
  float A2 = -__expf(alogs[(r * 256 + d) * 16 + n]) * 1.44269504f;
  float h = 0.f;
  for (int c = 0; c < 32; ++c) {
    float ss = spsum_g[((size_t)br * 32 + c) * 256 + d];
    size_t yo = (size_t)(br * 512 + d) * 1024 + c * 32 + n;
    float hin = h;
    h = fmaf(exp2f(ss * A2), h, Yc[yo]);
    Yc[yo] = hin;
  }
}

// Pass C: reuse sp from compact buffer; stage only tb/tc
__global__ void __launch_bounds__(256) k_scanC(
    const float* __restrict__ xseq, const float* __restrict__ xdT,
    const _Float16* __restrict__ sp16,
    const float* __restrict__ alogs, const float* __restrict__ ds_,
    float* __restrict__ Y) {
  int ch = blockIdx.x;
  int br = blockIdx.y; int r = br & 3;
  int d  = threadIdx.x;
  int rd = r * 256 + d;
  float A2[16], h[16];
#pragma unroll
  for (int n = 0; n < 16; ++n) A2[n] = -__expf(alogs[rd * 16 + n]) * 1.44269504f;
  float dsv = ds_[rd];
  __shared__ __align__(16) float t2[1024];   // [32c][32k'] tb+tc only
  __shared__ float yt[32][257];
  const float* xd = xdT + (size_t)(br * 32 + ch) * 1536;
  {
    int i = threadIdx.x;        // 256 f4 units
    int c = i >> 3, q = i & 7;
    ((f4*)t2)[c * 8 + q] = ((const f4*)xd)[c * 12 + 4 + q];
  }
  half8 spv[4];
  {
    const _Float16* spb = sp16 + (((size_t)(br * 32 + ch)) * 256 + d) * 32;
    spv[0] = *(const half8*)(spb);
    spv[1] = *(const half8*)(spb + 8);
    spv[2] = *(const half8*)(spb + 16);
    spv[3] = *(const half8*)(spb + 24);
  }
  float* ybase = Y + (size_t)(br * 512 + d) * 1024 + ch * 32;
#pragma unroll
  for (int n = 0; n < 16; ++n) h[n] = ybase[n];     // embedded carry
  __syncthreads();
  const float* us = xseq + (size_t)(br * 256 + d) * 1024 + ch * 32;
#pragma unroll
  for (int c4 = 0; c4 < 8; ++c4) {
    float4 uv = *(const float4*)(us + c4 * 4);
    float uarr[4] = {uv.x, uv.y, uv.z, uv.w};
#pragma unroll
    for (int cc = 0; cc < 4; ++cc) {
      int c = c4 * 4 + cc;
      float sp = (float)spv[c4 >> 1][(c4 & 1) * 4 + cc];
      float du = sp * uarr[cc];
      const f4* row = (const f4*)&t2[c * 32];
      f4 tb[4] = {row[0], row[1], row[2], row[3]};
      f4 tc[4] = {row[4], row[5], row[6], row[7]};
      float acc = 0.f;
#pragma unroll
      for (int n = 0; n < 16; ++n) {
        float e = exp2f(sp * A2[n]);
        h[n] = fmaf(e, h[n], du * tb[n >> 2][n & 3]);
        acc  = fmaf(h[n], tc[n >> 2][n & 3], acc);
      }
      yt[c][d] = fmaf(dsv, uarr[cc], acc);
    }
  }
  __syncthreads();
  for (int i = threadIdx.x; i < 2048; i += 256) {
    int dd = i >> 3, lq = i & 7;
    f4 v = {yt[lq * 4 + 0][dd], yt[lq * 4 + 1][dd], yt[lq * 4 + 2][dd], yt[lq * 4 + 3][dd]};
    *(f4*)(Y + (size_t)(br * 512 + dd) * 1024 + ch * 32 + lq * 4) = v;
  }
}

// ---------------- Y(rotated) -> fp16 un-rotated pix-major Ytg + fused cavg partials ----------------
__global__ void k_ytr(const float* __restrict__ Y, _Float16* __restrict__ Ytg,
                      float* __restrict__ cavg) {
  __shared__ float t[32][132];
  int l0  = blockIdx.x * 128;
  int ci0 = blockIdx.y * 32;
  int b   = blockIdx.z;
  int r   = ci0 >> 9;
  const float* src = Y + ((size_t)(b * 2048 + ci0)) * 1024 + l0;
#pragma unroll
  for (int i = 0; i < 16; ++i) {
    int idx = threadIdx.x + i * 256;
    int ci = idx >> 7, pp = idx & 127;
    t[ci][pp] = src[(size_t)ci * 1024 + pp];
  }
  __syncthreads();
  {
    int ci = threadIdx.x & 31, seg = threadIdx.x >> 5;
    float s = 0.f;
#pragma unroll
    for (int j = 0; j < 16; ++j) s += t[ci][seg * 16 + j];
    atomicAdd(&cavg[b * 2048 + ci0 + ci], s * (1.f / 1024.f));
  }
  int pp = threadIdx.x >> 1;
  int ch = (threadIdx.x & 1) * 16;
  _Float16 buf[16];
#pragma unroll
  for (int j = 0; j < 16; ++j) buf[j] = (_Float16)t[ch + j][pp];
  int pix = srcmap(r, l0 + pp);
  _Float16* dst = Ytg + ((size_t)(b * 1024) + pix) * 2048 + ci0 + ch;
  *(float4*)dst = *(const float4*)buf;
  *(float4*)(dst + 8) = *(const float4*)(buf + 8);
}

// ---------------- spatial-attn conv1 v6: LDS pads trimmed for 3 blocks/CU ----------------
__global__ void __launch_bounds__(256, 3) k_samfma(const _Float16* __restrict__ Ytg,
                                                   const _Float16* __restrict__ Whg2,
                                                   float* __restrict__ cpart) {
  __shared__ __align__(16) _Float16 As[6][32][36];   // 13.8 KB
  __shared__ __align__(16) _Float16 Bs[9][64][34];   // 39.2 KB (total 53.0 KB)
  int L = blockIdx.x;
  int ks = L & 7;
  int rem = L >> 3;             // 0..63
  int b = rem >> 3, rg = rem & 7;
  int tid = threadIdx.x;
  int wid = tid >> 6, lane = tid & 63;
  int r = lane & 15, g = lane >> 4;
  const _Float16* Yb = Ytg + (size_t)b * (1024 * 2048);
  const half8 zero8 = {0, 0, 0, 0, 0, 0, 0, 0};

  int srow[3], scol[3], sci8[3], srcoff[3]; bool sok[3];
#pragma unroll
  for (int i = 0; i < 3; ++i) {
    int unit = tid + i * 256;
    srow[i] = unit >> 7; scol[i] = (unit >> 2) & 31; sci8[i] = unit & 3;
    int grow = rg * 4 - 1 + srow[i];
    sok[i] = ((unsigned)grow < 32u);
    srcoff[i] = ((sok[i] ? grow : 0) * 32 + scol[i]) * 2048 + sci8[i] * 8;
  }
  int bcol = tid >> 2, bci8 = tid & 3;
  int ci_base = ks * 256;

  for (int coh = 0; coh < 2; ++coh) {
    f4 acc[2][4];
#pragma unroll
    for (int mi = 0; mi < 2; ++mi)
#pragma unroll
      for (int ni = 0; ni < 4; ++ni) acc[mi][ni] = (f4){0.f, 0.f, 0.f, 0.f};

    half8 pa[3], pb[9];
#pragma unroll
    for (int i = 0; i < 3; ++i) {
      half8 v = *(const half8*)(Yb + srcoff[i] + ci_base);
      pa[i] = sok[i] ? v : zero8;
    }
#pragma unroll
    for (int j = 0; j < 9; ++j)
      pb[j] = *(const half8*)(Whg2 + (((size_t)(j * 64 + ks * 8) * 128) + coh * 64 + bcol) * 32 + bci8 * 8);

    for (int ch = 0; ch < 8; ++ch) {
      __syncthreads();
#pragma unroll
      for (int i = 0; i < 3; ++i)
        *(half8*)&As[srow[i]][scol[i]][sci8[i] * 8] = pa[i];
#pragma unroll
      for (int j = 0; j < 9; ++j)
        *(half8*)&Bs[j][bcol][bci8 * 8] = pb[j];
      if (ch < 7) {
        int ci0 = ci_base + (ch + 1) * 32;
#pragma unroll
        for (int i = 0; i < 3; ++i) {
          half8 v = *(const half8*)(Yb + srcoff[i] + ci0);
          pa[i] = sok[i] ? v : zero8;
        }
        int cic = ks * 8 + ch + 1;
#pragma unroll
        for (int j = 0; j < 9; ++j)
          pb[j] = *(const half8*)(Whg2 + (((size_t)(j * 64 + cic) * 128) + coh * 64 + bcol) * 32 + bci8 * 8);
      }
      __syncthreads();

#pragma unroll
      for (int tap = 0; tap < 9; ++tap) {
        const int dh = tap / 3 - 1, dw = tap % 3 - 1;
        int lrow = wid + dh + 1;
        half8 av[2], bv[4];
#pragma unroll
        for (int mi = 0; mi < 2; ++mi) {
          int lcol = mi * 16 + r + dw;
          bool ok = ((unsigned)lcol < 32u);
          half8 v = *(const half8*)&As[lrow][lcol & 31][g * 8];
          av[mi] = ok ? v : zero8;
        }
#pragma unroll
        for (int ni = 0; ni < 4; ++ni)
          bv[ni] = *(const half8*)&Bs[tap][ni * 16 + r][g * 8];
#pragma unroll
        for (int mi = 0; mi < 2; ++mi)
#pragma unroll
          for (int ni = 0; ni < 4; ++ni)
            acc[mi][ni] = __builtin_amdgcn_mfma_f32_16x16x32_f16(av[mi], bv[ni], acc[mi][ni], 0, 0, 0);
      }
    }

    float* cp = cpart + (size_t)ks * (8192 * 128);
    int basepix = b * 1024 + (rg * 4 + wid) * 32;
#pragma unroll
    for (int mi = 0; mi < 2; ++mi)
#pragma unroll
      for (int ni = 0; ni < 4; ++ni) {
        int co = coh * 64 + ni * 16 + r;
#pragma unroll
        for (int j = 0; j < 4; ++j)
          cp[(size_t)(basepix + mi * 16 + g * 4 + j) * 128 + co] = acc[mi][ni][j];
      }
    __syncthreads();
  }
}

// ---------------- reduce 8 partials + bias + relu + conv2 + softmax ----------------
__global__ void __launch_bounds__(256) k_saconv2f(const float* __restrict__ cpart,
                                                  const float* __restrict__ sab1,
                                                  const float* __restrict__ saw2,
                                                  const float* __restrict__ sab2,
                                                  float* __restrict__ swout) {
  int tid = threadIdx.x;
  int pixg = tid >> 3, cig = tid & 7;
  int p = blockIdx.x * 32 + pixg;
  int b = blockIdx.y;
  int pix = b * 1024 + p;
  const float* c0 = cpart + (size_t)pix * 128 + cig * 16;
  float a0 = 0.f, a1 = 0.f, a2 = 0.f, a3 = 0.f;
#pragma unroll
  for (int j4 = 0; j4 < 4; ++j4) {
    float sx = 0.f, sy = 0.f, sz = 0.f, sw_ = 0.f;
#pragma unroll
    for (int k = 0; k < 8; ++k) {
      float4 v = *(const float4*)(c0 + (size_t)k * 1048576 + j4 * 4);
      sx += v.x; sy += v.y; sz += v.z; sw_ += v.w;
    }
    int ci = cig * 16 + j4 * 4;
    float v0 = fmaxf(sx + sab1[ci],     0.f);
    float v1 = fmaxf(sy + sab1[ci + 1], 0.f);
    float v2 = fmaxf(sz + sab1[ci + 2], 0.f);
    float v3 = fmaxf(sw_ + sab1[ci + 3], 0.f);
    a0 = fmaf(v0, saw2[ci], fmaf(v1, saw2[ci+1], fmaf(v2, saw2[ci+2], fmaf(v3, saw2[ci+3], a0))));
    a1 = fmaf(v0, saw2[128+ci], fmaf(v1, saw2[128+ci+1], fmaf(v2, saw2[128+ci+2], fmaf(v3, saw2[128+ci+3], a1))));
    a2 = fmaf(v0, saw2[256+ci], fmaf(v1, saw2[256+ci+1], fmaf(v2, saw2[256+ci+2], fmaf(v3, saw2[256+ci+3], a2))));
    a3 = fmaf(v0, saw2[384+ci], fmaf(v1, saw2[384+ci+1], fmaf(v2, saw2[384+ci+2], fmaf(v3, saw2[384+ci+3], a3))));
  }
#pragma unroll
  for (int off = 4; off > 0; off >>= 1) {
    a0 += __shfl_down(a0, off, 8);
    a1 += __shfl_down(a1, off, 8);
    a2 += __shfl_down(a2, off, 8);
    a3 += __shfl_down(a3, off, 8);
  }
  if (cig == 0) {
    a0 += sab2[0]; a1 += sab2[1]; a2 += sab2[2]; a3 += sab2[3];
    float m = fmaxf(fmaxf(a0, a1), fmaxf(a2, a3));
    float e0 = __expf(a0 - m), e1 = __expf(a1 - m), e2 = __expf(a2 - m), e3 = __expf(a3 - m);
    float inv = 1.f / (e0 + e1 + e2 + e3);
    swout[(b * 4 + 0) * 1024 + p] = e0 * inv;
    swout[(b * 4 + 1) * 1024 + p] = e1 * inv;
    swout[(b * 4 + 2) * 1024 + p] = e2 * inv;
    swout[(b * 4 + 3) * 1024 + p] = e3 * inv;
  }
}

// ---------------- channel attention ----------------
__global__ void k_cw(const float* __restrict__ cavg, const float* __restrict__ caw1,
                     const float* __restrict__ caw2, float* __restrict__ cwout) {
  int b = blockIdx.x;
  int t = threadIdx.x;
  __shared__ float hid[32];
  __shared__ float vv[4];
  if (t < 32) {
    float a = 0.f;
    const float* cv = cavg + b * 2048;
    const float* wr = caw1 + t * 2048;
    for (int i = 0; i < 2048; ++i) a = fmaf(wr[i], cv[i], a);
    hid[t] = fmaxf(a, 0.f);
  }
  __syncthreads();
  if (t < 4) {
    float a = 0.f;
    for (int i = 0; i < 32; ++i) a = fmaf(caw2[t * 32 + i], hid[i], a);
    vv[t] = a;
  }
  __syncthreads();
  if (t < 4) {
    float m = fmaxf(fmaxf(vv[0], vv[1]), fmaxf(vv[2], vv[3]));
    float e = __expf(vv[t] - m);
    float s = __expf(vv[0] - m) + __expf(vv[1] - m) + __expf(vv[2] - m) + __expf(vv[3] - m);
    cwout[b * 4 + t] = e / s;
  }
}

// ---------------- catH: mixes from Ytg (fp16, un-rotated) -> fp16 pix-major concat ----------------
__global__ void __launch_bounds__(256) k_catH(const _Float16* __restrict__ Ytg,
                                              const float* __restrict__ swv,
                                              const float* __restrict__ cwv,
                                              _Float16* __restrict__ catO) {
  int p0 = blockIdx.x * 64, c0 = blockIdx.y * 64, b = blockIdx.z;
  int pp = threadIdx.x >> 2, cs = (threadIdx.x & 3) * 16;
  int pix = p0 + pp;
  const _Float16* src = Ytg + (size_t)(b * 1024 + pix) * 2048 + c0 + cs;
  float accS[16], accC[16];
#pragma unroll
  for (int j = 0; j < 16; ++j) { accS[j] = 0.f; accC[j] = 0.f; }
#pragma unroll
  for (int r = 0; r < 4; ++r) {
    half8 v0 = *(const half8*)(src + r * 512);
    half8 v1 = *(const half8*)(src + r * 512 + 8);
    float sw = swv[(size_t)(b * 4 + r) * 1024 + pix];
    float cw = cwv[b * 4 + r];
#pragma unroll
    for (int j = 0; j < 8; ++j) {
      float f0 = (float)v0[j], f1 = (float)v1[j];
      accS[j]     = fmaf(f0, sw, accS[j]);
      accS[j + 8] = fmaf(f1, sw, accS[j + 8]);
      accC[j]     = fmaf(f0, cw, accC[j]);
      accC[j + 8] = fmaf(f1, cw, accC[j + 8]);
    }
  }
  _Float16 os[16], oc[16];
#pragma unroll
  for (int j = 0; j < 16; ++j) { os[j] = (_Float16)accS[j]; oc[j] = (_Float16)accC[j]; }
  _Float16* dst = catO + ((size_t)(b * 1024) + pix) * 1024;
  *(half8*)(dst + c0 + cs)       = *(half8*)os;
  *(half8*)(dst + c0 + cs + 8)   = *(half8*)(os + 8);
  *(half8*)(dst + 512 + c0 + cs)     = *(half8*)oc;
  *(half8*)(dst + 512 + c0 + cs + 8) = *(half8*)(oc + 8);
}

// ---------------- gate 1x1 conv (1024->512) via MFMA + sigmoid fuse -> fusedH ----------------
__global__ void __launch_bounds__(256) k_gatemfma(const _Float16* __restrict__ catO,
                                                  const _Float16* __restrict__ gwH,
                                                  const float* __restrict__ gb,
                                                  _Float16* __restrict__ fusedH) {
  int wid = threadIdx.x >> 6, lane = threadIdx.x & 63;
  int r = lane & 15, g = lane >> 4;
  int p0 = blockIdx.x * 128 + (wid >> 1) * 64;
  int c0 = blockIdx.y * 128 + (wid & 1) * 64;
  int b  = blockIdx.z;
  const _Float16* Cb = catO + (size_t)b * (1024 * 1024);
  f4 acc[4][4];
#pragma unroll
  for (int mi = 0; mi < 4; ++mi)
#pragma unroll
    for (int ni = 0; ni < 4; ++ni) acc[mi][ni] = (f4){0.f, 0.f, 0.f, 0.f};
  for (int kk = 0; kk < 1024; kk += 32) {
    half8 av[4], bv[4];
#pragma unroll
    for (int mi = 0; mi < 4; ++mi)
      av[mi] = *(const half8*)(Cb + (size_t)(p0 + mi * 16 + r) * 1024 + kk + g * 8);
#pragma unroll
    for (int ni = 0; ni < 4; ++ni)
      bv[ni] = *(const half8*)(gwH + (size_t)(c0 + ni * 16 + r) * 1024 + kk + g * 8);
#pragma unroll
    for (int mi = 0; mi < 4; ++mi)
#pragma unroll
      for (int ni = 0; ni < 4; ++ni)
        acc[mi][ni] = __builtin_amdgcn_mfma_f32_16x16x32_f16(av[mi], bv[ni], acc[mi][ni], 0, 0, 0);
  }
#pragma unroll
  for (int ni = 0; ni < 4; ++ni) {
    int c = c0 + ni * 16 + r;
    float bias = gb[c];
#pragma unroll
    for (int mi = 0; mi < 4; ++mi)
#pragma unroll
      for (int j = 0; j < 4; ++j) {
        int pix = p0 + mi * 16 + g * 4 + j;
        const _Float16* rowp = Cb + (size_t)pix * 1024 + c;
        float sp = (float)rowp[0], ch = (float)rowp[512];
        float gt = sigmoidf_(acc[mi][ni][j] + bias);
        fusedH[((size_t)(b * 1024) + pix) * 512 + c] = (_Float16)(gt * sp + (1.f - gt) * ch);
      }
  }
}

// ---------------- out_proj (512->256) via MFMA + GELU ----------------
__global__ void __launch_bounds__(256) k_outprojmfma(const _Float16* __restrict__ fusedH,
                                                     const _Float16* __restrict__ opH,
                                                     float* __restrict__ out) {
  int wid = threadIdx.x >> 6, lane = threadIdx.x & 63;
  int r = lane & 15, g = lane >> 4;
  int m0 = blockIdx.x * 64;
  int n0 = blockIdx.y * 256 + wid * 64;
  int b  = blockIdx.z;
  f4 acc[4][4];
#pragma unroll
  for (int mi = 0; mi < 4; ++mi)
#pragma unroll
    for (int ni = 0; ni < 4; ++ni) acc[mi][ni] = (f4){0.f, 0.f, 0.f, 0.f};
  for (int kk = 0; kk < 512; kk += 32) {
    half8 av[4], bv[4];
#pragma unroll
    for (int mi = 0; mi < 4; ++mi)
      av[mi] = *(const half8*)(opH + (size_t)(m0 + mi * 16 + r) * 512 + kk + g * 8);
#pragma unroll
    for (int ni = 0; ni < 4; ++ni)
      bv[ni] = *(const half8*)(fusedH + ((size_t)(b * 1024) + n0 + ni * 16 + r) * 512 + kk + g * 8);
#pragma unroll
    for (int mi = 0; mi < 4; ++mi)
#pragma unroll
      for (int ni = 0; ni < 4; ++ni)
        acc[mi][ni] = __builtin_amdgcn_mfma_f32_16x16x32_f16(av[mi], bv[ni], acc[mi][ni], 0, 0, 0);
  }
#pragma unroll
  for (int mi = 0; mi < 4; ++mi)
#pragma unroll
    for (int ni = 0; ni < 4; ++ni) {
      int pix = n0 + ni * 16 + r;
#pragma unroll
      for (int j = 0; j < 4; ++j) {
        int co = m0 + mi * 16 + g * 4 + j;
        out[((size_t)(b * 256) + co) * 1024 + pix] = geluf(acc[mi][ni][j]);
      }
    }
}

extern "C" void kernel_launch(void* const* d_in, const int* in_sizes, int n_in,
                              void* d_out, int out_size, void* d_ws, size_t ws_size,
                              hipStream_t stream) {
  const float* x    = (const float*)d_in[0];
  const float* inw  = (const float*)d_in[1];
  const float* opw  = (const float*)d_in[2];
  const float* cxw  = (const float*)d_in[3];
  const float* cxb  = (const float*)d_in[4];
  const float* czw  = (const float*)d_in[5];
  const float* czb  = (const float*)d_in[6];
  const float* xpw  = (const float*)d_in[7];
  const float* dtw  = (const float*)d_in[8];
  const float* dtb  = (const float*)d_in[9];
  const float* alog = (const float*)d_in[10];
  const float* ds   = (const float*)d_in[11];
  const float* saw1 = (const float*)d_in[12];
  const float* sab1 = (const float*)d_in[13];
  const float* saw2 = (const float*)d_in[14];
  const float* sab2 = (const float*)d_in[15];
  const float* caw1 = (const float*)d_in[16];
  const float* caw2 = (const float*)d_in[17];
  const float* gw   = (const float*)d_in[18];
  const float* gb   = (const float*)d_in[19];

  float* ws = (float*)d_ws;
  float* xz   = ws + 0;          //  4,194,304  [alias: sp16 fp16 -> catO fp16]
  float* xseq = ws + 4194304;    //  8,388,608  [alias: Ytg fp16 -> fusedH fp16]
  float* xdT  = ws + 12582912;   //  1,572,864
  float* Y    = ws + 14155776;   // 16,777,216  [alias: xTh/xTl pre-conv] rotated; carries; Cpart
  float* spsum= ws + 30932992;   //    262,144
  float* swb  = ws + 31981568;   //     32,768
  float* cavg = ws + 32014336;   //     16,384
  float* cwb  = ws + 32030720;   //         32
  float* inWHL= ws + 32030752;   //    131,072 (inwH + inwL fp16)
  float* opHF = ws + 32161824;   //    131,072 (opH fp16)
  float* gwHF = ws + 32292896;   //    524,288 (gwH fp16)
  float* WhgF = ws + 32817184;   //  1,179,648 (Whg2 fp16)
  float* Cpart  = Y;             //  8,388,608 (8ks x 8192pix x 128co)
  _Float16* sp16   = (_Float16*)xz;      // 8,388,608 halves
  _Float16* Ytg    = (_Float16*)xseq;
  _Float16* catO   = (_Float16*)xz;      // after scanC consumed sp16
  _Float16* fusedH = (_Float16*)xseq;
  _Float16* Whg2 = (_Float16*)WhgF;
  _Float16* gwH = (_Float16*)gwHF;
  _Float16* opH = (_Float16*)opHF;
  _Float16* inwH = (_Float16*)inWHL;
  _Float16* inwL = (_Float16*)(inWHL + 65536);
  _Float16* xTh  = (_Float16*)Y;
  _Float16* xTl  = (_Float16*)(Y + 1048576);

  k_prep<<<12352, 256, 0, stream>>>(inw, gw, opw, saw1, inwH, inwL, gwH, opH, cavg, Whg2);
  k_xT<<<dim3(8, 8, 8), 256, 0, stream>>>(x, xTh, xTl);
  k_inprojmfma<<<dim3(4, 8, 8), 256, 0, stream>>>(xTh, xTl, inwH, inwL, xz);
  k_conv<<<dim3(256, 8), 256, 0, stream>>>(xz, cxw, cxb, czw, czb, xseq, Y);
  k_xdblT<<<dim3(32, 32), 256, 0, stream>>>(xseq, xpw, xdT);
  k_scanA<<<dim3(32, 32), 256, 0, stream>>>(xseq, xdT, dtw, dtb, alog, spsum, sp16, Y);
  k_scanB<<<512, 256, 0, stream>>>(spsum, alog, Y);
  k_scanC<<<dim3(32, 32), 256, 0, stream>>>(xseq, xdT, sp16, alog, ds, Y);
  k_ytr<<<dim3(8, 64, 8), 256, 0, stream>>>(Y, Ytg, cavg);
  k_cw<<<8, 64, 0, stream>>>(cavg, caw1, caw2, cwb);
  k_samfma<<<512, 256, 0, stream>>>(Ytg, Whg2, Cpart);
  k_saconv2f<<<dim3(32, 8), 256, 0, stream>>>(Cpart, sab1, saw2, sab2, swb);
  k_catH<<<dim3(16, 8, 8), 256, 0, stream>>>(Ytg, swb, cwb, catO);
  k_gatemfma<<<dim3(8, 4, 8), 256, 0, stream>>>(catO, gwH, gb, fusedH);
  k_outprojmfma<<<dim3(4, 4, 8), 256, 0, stream>>>(fusedH, opH, (float*)d_out);
}

// Round 18
// 422.326 us; speedup vs baseline: 1.1233x; 1.1233x over previous
//
#include <hip/hip_runtime.h>
#include <math.h>

// dims: B=8, DM=256, H=W=32, L=HW=1024, R=4, DI=512, DH=256, N=16, K=4, DTR=16

typedef _Float16 half8 __attribute__((ext_vector_type(8)));
typedef float f4 __attribute__((ext_vector_type(4)));

__device__ __forceinline__ int srcmap(int r, int l) {
  int i = l >> 5, j = l & 31;
  int h, w;
  if (r == 0)      { h = i;      w = j;      }
  else if (r == 1) { h = j;      w = 31 - i; }
  else if (r == 2) { h = 31 - i; w = 31 - j; }
  else             { h = 31 - j; w = i;      }
  return (h << 5) + w;
}

__device__ __forceinline__ float siluf(float x)    { return x / (1.f + __expf(-x)); }
__device__ __forceinline__ float sigmoidf_(float x){ return 1.f / (1.f + __expf(-x)); }
__device__ __forceinline__ float geluf(float x) {
  float x3 = x * x * x;
  return 0.5f * x * (1.f + tanhf(0.7978845608028654f * (x + 0.044715f * x3)));
}

// ---------------- prep (merged): inw split, gwH/opH casts, cavg zero, sa_w1 pack ----------------
__global__ void k_prep(const float* __restrict__ inw, const float* __restrict__ gw,
                       const float* __restrict__ opw, const float* __restrict__ saw1,
                       _Float16* __restrict__ inwH, _Float16* __restrict__ inwL,
                       _Float16* __restrict__ gwH, _Float16* __restrict__ opH,
                       float* __restrict__ cavg, _Float16* __restrict__ Whg2) {
  int idx = blockIdx.x * 256 + threadIdx.x;
  if (idx < 131072) {
    float v = inw[idx];
    _Float16 h = (_Float16)v;
    inwH[idx] = h;
    inwL[idx] = (_Float16)(v - (float)h);
  } else if (idx < 655360) {
    int i = idx - 131072;
    gwH[i] = (_Float16)gw[i];
  } else if (idx < 786432) {
    int i = idx - 655360;
    opH[i] = (_Float16)opw[i];
  } else if (idx < 802816) {
    cavg[idx - 786432] = 0.f;
  } else if (idx < 3162112) {
    int o = idx - 802816;            // < 2,359,296
    int ci = o & 2047;
    int co = (o >> 11) & 127;
    int tap = o >> 18;
    size_t dst = (((size_t)(tap * 64 + (ci >> 5)) * 128) + co) * 32 + (ci & 31);
    Whg2[dst] = (_Float16)saw1[((size_t)co * 2048 + ci) * 9 + tap];
  }
}

// ---------------- x -> pix-major fp16 hi/lo pair: xTh/xTl[b][pix][c] ----------------
__global__ void __launch_bounds__(256) k_xT(const float* __restrict__ x,
                                            _Float16* __restrict__ xTh,
                                            _Float16* __restrict__ xTl) {
  __shared__ float t[32][132];
  int p0 = blockIdx.x * 128, c0 = blockIdx.y * 32, b = blockIdx.z;
  const float* src = x + ((size_t)(b * 256 + c0)) * 1024 + p0;
#pragma unroll
  for (int i = 0; i < 16; ++i) {
    int idx = threadIdx.x + i * 256;
    int ci = idx >> 7, pp = idx & 127;
    t[ci][pp] = src[(size_t)ci * 1024 + pp];
  }
  __syncthreads();
  int pp = threadIdx.x >> 1;
  int ch = (threadIdx.x & 1) * 16;
  _Float16 bh[16], bl[16];
#pragma unroll
  for (int j = 0; j < 16; ++j) {
    float f = t[ch + j][pp];
    _Float16 h = (_Float16)f;
    bh[j] = h;
    bl[j] = (_Float16)(f - (float)h);
  }
  size_t o = ((size_t)(b * 1024) + p0 + pp) * 256 + c0 + ch;
  *(half8*)(xTh + o)     = *(half8*)bh;
  *(half8*)(xTh + o + 8) = *(half8*)(bh + 8);
  *(half8*)(xTl + o)     = *(half8*)bl;
  *(half8*)(xTl + o + 8) = *(half8*)(bl + 8);
}

// ---------------- in_proj via split-fp16 MFMA (fp32-accurate): xz[b][d][pix] ----------------
__global__ void __launch_bounds__(256) k_inprojmfma(const _Float16* __restrict__ xTh,
                                                    const _Float16* __restrict__ xTl,
                                                    const _Float16* __restrict__ inwH,
                                                    const _Float16* __restrict__ inwL,
                                                    float* __restrict__ xz) {
  int wid = threadIdx.x >> 6, lane = threadIdx.x & 63;
  int r = lane & 15, g = lane >> 4;
  int m0 = blockIdx.x * 128 + (wid >> 1) * 64;   // d
  int n0 = blockIdx.y * 128 + (wid & 1) * 64;    // pix
  int b  = blockIdx.z;
  f4 acc[4][4];
#pragma unroll
  for (int mi = 0; mi < 4; ++mi)
#pragma unroll
    for (int ni = 0; ni < 4; ++ni) acc[mi][ni] = (f4){0.f, 0.f, 0.f, 0.f};
  for (int kk = 0; kk < 256; kk += 32) {
    half8 ah[4], al[4], bh[4], bl[4];
#pragma unroll
    for (int mi = 0; mi < 4; ++mi) {
      size_t o = (size_t)(m0 + mi * 16 + r) * 256 + kk + g * 8;
      ah[mi] = *(const half8*)(inwH + o);
      al[mi] = *(const half8*)(inwL + o);
    }
#pragma unroll
    for (int ni = 0; ni < 4; ++ni) {
      size_t o = ((size_t)(b * 1024) + n0 + ni * 16 + r) * 256 + kk + g * 8;
      bh[ni] = *(const half8*)(xTh + o);
      bl[ni] = *(const half8*)(xTl + o);
    }
#pragma unroll
    for (int mi = 0; mi < 4; ++mi)
#pragma unroll
      for (int ni = 0; ni < 4; ++ni) {
        acc[mi][ni] = __builtin_amdgcn_mfma_f32_16x16x32_f16(ah[mi], bh[ni], acc[mi][ni], 0, 0, 0);
        acc[mi][ni] = __builtin_amdgcn_mfma_f32_16x16x32_f16(ah[mi], bl[ni], acc[mi][ni], 0, 0, 0);
        acc[mi][ni] = __builtin_amdgcn_mfma_f32_16x16x32_f16(al[mi], bh[ni], acc[mi][ni], 0, 0, 0);
      }
  }
#pragma unroll
  for (int mi = 0; mi < 4; ++mi)
#pragma unroll
    for (int ni = 0; ni < 4; ++ni) {
      int pix = n0 + ni * 16 + r;
#pragma unroll
      for (int j = 0; j < 4; ++j) {
        int d = m0 + mi * 16 + g * 4 + j;
        xz[((size_t)(b * 512) + d) * 1024 + pix] = acc[mi][ni][j];
      }
    }
}

// ---------------- merged depthwise conv1d + SiLU (x- and z-halves), LDS-tiled ----------------
__global__ void __launch_bounds__(256) k_conv(const float* __restrict__ xz,
                                              const float* __restrict__ cxw,
                                              const float* __restrict__ cxb,
                                              const float* __restrict__ czw,
                                              const float* __restrict__ czb,
                                              float* __restrict__ xseq,
                                              float* __restrict__ Y) {
  int d = blockIdx.x;   // 0..255
  int b = blockIdx.y;   // 0..7
  __shared__ float xs_t[1024];
  __shared__ float zs_t[1024];
  int t4 = threadIdx.x * 4;
  *(float4*)&xs_t[t4] = *(const float4*)(xz + ((size_t)(b * 512 + d)) * 1024 + t4);
  *(float4*)&zs_t[t4] = *(const float4*)(xz + ((size_t)(b * 512 + 256 + d)) * 1024 + t4);
  __syncthreads();
#pragma unroll
  for (int r = 0; r < 4; ++r) {
    int rd = r * 256 + d;
    float xw0 = cxw[rd*4+0], xw1 = cxw[rd*4+1], xw2 = cxw[rd*4+2], xw3 = cxw[rd*4+3];
    float zw0 = czw[rd*4+0], zw1 = czw[rd*4+1], zw2 = czw[rd*4+2], zw3 = czw[rd*4+3];
    float xbi = cxb[rd], zbi = czb[rd];
    float xo[4], zo[4];
#pragma unroll
    for (int q = 0; q < 4; ++q) {
      int l = t4 + q;
      float ax = xbi, az = zbi;
      if (l - 1 >= 0) {
        int s = srcmap(r, l - 1);
        ax = fmaf(xw0, xs_t[s], ax); az = fmaf(zw0, zs_t[s], az);
      }
      {
        int s = srcmap(r, l);
        ax = fmaf(xw1, xs_t[s], ax); az = fmaf(zw1, zs_t[s], az);
      }
      if (l + 1 < 1024) {
        int s = srcmap(r, l + 1);
        ax = fmaf(xw2, xs_t[s], ax); az = fmaf(zw2, zs_t[s], az);
      }
      if (l + 2 < 1024) {
        int s = srcmap(r, l + 2);
        ax = fmaf(xw3, xs_t[s], ax); az = fmaf(zw3, zs_t[s], az);
      }
      xo[q] = siluf(ax); zo[q] = siluf(az);
    }
    *(float4*)(xseq + ((size_t)(b * 4 + r) * 256 + d) * 1024 + t4) = *(float4*)xo;
    *(float4*)(Y + ((size_t)(b * 4 + r) * 512 + 256 + d) * 1024 + t4) = *(float4*)zo;
  }
}

// ---------------- x_dbl v2: LDS-staged x-tile, f4 weight loads; xdT[br][ch][32c][48k] ----------------
__global__ void __launch_bounds__(256) k_xdblT(const float* __restrict__ xseq,
                                               const float* __restrict__ xpw,
                                               float* __restrict__ xdT) {
  int ch = blockIdx.x;          // 0..31
  int br = blockIdx.y;          // 0..31
  int r  = br & 3;
  __shared__ float xs_t[256][33];
  const float* base = xseq + (size_t)(br * 256) * 1024 + ch * 32;
  {
    int c4 = threadIdx.x & 7;
    int drow = threadIdx.x >> 3;
#pragma unroll
    for (int p = 0; p < 8; ++p) {
      int dd = p * 32 + drow;
      float4 v = *(const float4*)(base + (size_t)dd * 1024 + c4 * 4);
      xs_t[dd][c4*4+0] = v.x; xs_t[dd][c4*4+1] = v.y;
      xs_t[dd][c4*4+2] = v.z; xs_t[dd][c4*4+3] = v.w;
    }
  }
  __syncthreads();
  int c  = threadIdx.x & 31;
  int kq = threadIdx.x >> 5;    // 0..7, 6 k each
  const float* w = xpw + (r * 48 + kq * 6) * 256;
  float acc[6] = {0.f, 0.f, 0.f, 0.f, 0.f, 0.f};
  for (int d0 = 0; d0 < 256; d0 += 4) {
    float x0 = xs_t[d0][c], x1 = xs_t[d0+1][c], x2 = xs_t[d0+2][c], x3 = xs_t[d0+3][c];
#pragma unroll
    for (int j = 0; j < 6; ++j) {
      float4 wv = *(const float4*)(w + j * 256 + d0);
      acc[j] = fmaf(wv.x, x0, fmaf(wv.y, x1, fmaf(wv.z, x2, fmaf(wv.w, x3, acc[j]))));
    }
  }
  float* o = xdT + ((size_t)(br * 32 + ch) * 32 + c) * 48 + kq * 6;
#pragma unroll
  for (int j = 0; j < 6; ++j) o[j] = acc[j];
}

// ---------------- chunked selective scan (chunk=32) ----------------
// Pass A: chunk-local end-state (h0=0); stores spsum and packed fp16 sp (compact coalesced)
__global__ void __launch_bounds__(256) k_scanA(
    const float* __restrict__ xseq, const float* __restrict__ xdT,
    const float* __restrict__ dtw_, const float* __restrict__ dtb_,
    const float* __restrict__ alogs,
    float* __restrict__ spsum_g, _Float16* __restrict__ sp16,
    float* __restrict__ Yc) {
  int ch = blockIdx.x;
  int br = blockIdx.y; int r = br & 3;
  int d  = threadIdx.x;
  int rd = r * 256 + d;
  f4 w0 = *(const f4*)&dtw_[rd * 16], w1 = *(const f4*)&dtw_[rd * 16 + 4],
     w2 = *(const f4*)&dtw_[rd * 16 + 8], w3 = *(const f4*)&dtw_[rd * 16 + 12];
  float A2[16], h[16];
#pragma unroll
  for (int n = 0; n < 16; ++n) A2[n] = -__expf(alogs[rd * 16 + n]) * 1.44269504f;
#pragma unroll
  for (int n = 0; n < 16; ++n) h[n] = 0.f;
  float spsum = 0.f;
  float bias = dtb_[rd];
  half8 sph[4];
  __shared__ __align__(16) float t2[1536];
  const float* xd = xdT + (size_t)(br * 32 + ch) * 1536;
  {
    int i = threadIdx.x;        // 256 f4 units: c = i>>3, k4 = i&7 (k in [0,32))
    int c = i >> 3, k4 = i & 7;
    ((f4*)t2)[c * 12 + k4] = ((const f4*)xd)[c * 12 + k4];
  }
  __syncthreads();
  const float* us = xseq + (size_t)(br * 256 + d) * 1024 + ch * 32;
#pragma unroll
  for (int c4 = 0; c4 < 8; ++c4) {
    float4 uv = *(const float4*)(us + c4 * 4);
    float uarr[4] = {uv.x, uv.y, uv.z, uv.w};
#pragma unroll
    for (int cc = 0; cc < 4; ++cc) {
      const f4* row = (const f4*)&t2[(c4 * 4 + cc) * 48];
      f4 td0 = row[0], td1 = row[1], td2 = row[2], td3 = row[3];
      float delta = bias
        + td0[0]*w0[0] + td0[1]*w0[1] + td0[2]*w0[2] + td0[3]*w0[3]
        + td1[0]*w1[0] + td1[1]*w1[1] + td1[2]*w1[2] + td1[3]*w1[3]
        + td2[0]*w2[0] + td2[1]*w2[1] + td2[2]*w2[2] + td2[3]*w2[3]
        + td3[0]*w3[0] + td3[1]*w3[1] + td3[2]*w3[2] + td3[3]*w3[3];
      float sp = (delta > 20.f) ? delta : __logf(1.f + __expf(delta));
      sph[c4 >> 1][(c4 & 1) * 4 + cc] = (_Float16)sp;
      float du = sp * uarr[cc];
      spsum += sp;
      f4 tb[4] = {row[4], row[5], row[6], row[7]};
#pragma unroll
      for (int n = 0; n < 16; ++n) {
        float e = exp2f(sp * A2[n]);
        h[n] = fmaf(e, h[n], du * tb[n >> 2][n & 3]);
      }
    }
  }
  spsum_g[((size_t)br * 32 + ch) * 256 + d] = spsum;
  _Float16* spo = sp16 + (((size_t)(br * 32 + ch)) * 256 + d) * 32;
  *(f4*)(spo)      = *(f4*)&sph[0];
  *(f4*)(spo + 8)  = *(f4*)&sph[1];
  *(f4*)(spo + 16) = *(f4*)&sph[2];
  *(f4*)(spo + 24) = *(f4*)&sph[3];
  float* hco = Yc + (size_t)(br * 512 + d) * 1024 + ch * 32;
#pragma unroll
  for (int n = 0; n < 16; ++n) hco[n] = h[n];
}

// Pass B: prefix over chunks; aprod recomputed from spsum
__global__ void k_scanB(const float* __restrict__ spsum_g, const float* __restrict__ alogs,
                        float* __restrict__ Yc) {
  int t  = blockIdx.x * 256 + threadIdx.x;   // br*4096 + d*16 + n
  int br = t >> 12;
  int dn = t & 4095;
  int d = dn >> 4, n = dn & 15;
  int r = br & 3;
  float A2 = -__expf(alogs[(r * 256 + d) * 16 + n]) * 1.44269504f;
  float h = 0.f;
  for (int c = 0; c < 32; ++c) {
    float ss = spsum_g[((size_t)br * 32 + c) * 256 + d];
    size_t yo = (size_t)(br * 512 + d) * 1024 + c * 32 + n;
    float hin = h;
    h = fmaf(exp2f(ss * A2), h, Yc[yo]);
    Yc[yo] = hin;
  }
}

// Pass C: reuse sp from compact buffer; stage only tb/tc
__global__ void __launch_bounds__(256) k_scanC(
    const float* __restrict__ xseq, const float* __restrict__ xdT,
    const _Float16* __restrict__ sp16,
    const float* __restrict__ alogs, const float* __restrict__ ds_,
    float* __restrict__ Y) {
  int ch = blockIdx.x;
  int br = blockIdx.y; int r = br & 3;
  int d  = threadIdx.x;
  int rd = r * 256 + d;
  float A2[16], h[16];
#pragma unroll
  for (int n = 0; n < 16; ++n) A2[n] = -__expf(alogs[rd * 16 + n]) * 1.44269504f;
  float dsv = ds_[rd];
  __shared__ __align__(16) float t2[1024];   // [32c][32k'] tb+tc only
  __shared__ float yt[32][257];
  const float* xd = xdT + (size_t)(br * 32 + ch) * 1536;
  {
    int i = threadIdx.x;        // 256 f4 units
    int c = i >> 3, q = i & 7;
    ((f4*)t2)[c * 8 + q] = ((const f4*)xd)[c * 12 + 4 + q];
  }
  half8 spv[4];
  {
    const _Float16* spb = sp16 + (((size_t)(br * 32 + ch)) * 256 + d) * 32;
    spv[0] = *(const half8*)(spb);
    spv[1] = *(const half8*)(spb + 8);
    spv[2] = *(const half8*)(spb + 16);
    spv[3] = *(const half8*)(spb + 24);
  }
  float* ybase = Y + (size_t)(br * 512 + d) * 1024 + ch * 32;
#pragma unroll
  for (int n = 0; n < 16; ++n) h[n] = ybase[n];     // embedded carry
  __syncthreads();
  const float* us = xseq + (size_t)(br * 256 + d) * 1024 + ch * 32;
#pragma unroll
  for (int c4 = 0; c4 < 8; ++c4) {
    float4 uv = *(const float4*)(us + c4 * 4);
    float uarr[4] = {uv.x, uv.y, uv.z, uv.w};
#pragma unroll
    for (int cc = 0; cc < 4; ++cc) {
      int c = c4 * 4 + cc;
      float sp = (float)spv[c4 >> 1][(c4 & 1) * 4 + cc];
      float du = sp * uarr[cc];
      const f4* row = (const f4*)&t2[c * 32];
      f4 tb[4] = {row[0], row[1], row[2], row[3]};
      f4 tc[4] = {row[4], row[5], row[6], row[7]};
      float acc = 0.f;
#pragma unroll
      for (int n = 0; n < 16; ++n) {
        float e = exp2f(sp * A2[n]);
        h[n] = fmaf(e, h[n], du * tb[n >> 2][n & 3]);
        acc  = fmaf(h[n], tc[n >> 2][n & 3], acc);
      }
      yt[c][d] = fmaf(dsv, uarr[cc], acc);
    }
  }
  __syncthreads();
  for (int i = threadIdx.x; i < 2048; i += 256) {
    int dd = i >> 3, lq = i & 7;
    f4 v = {yt[lq * 4 + 0][dd], yt[lq * 4 + 1][dd], yt[lq * 4 + 2][dd], yt[lq * 4 + 3][dd]};
    *(f4*)(Y + (size_t)(br * 512 + dd) * 1024 + ch * 32 + lq * 4) = v;
  }
}

// ---------------- Y(rotated) -> fp16 un-rotated pix-major Ytg + fused cavg partials ----------------
__global__ void k_ytr(const float* __restrict__ Y, _Float16* __restrict__ Ytg,
                      float* __restrict__ cavg) {
  __shared__ float t[32][132];
  int l0  = blockIdx.x * 128;
  int ci0 = blockIdx.y * 32;
  int b   = blockIdx.z;
  int r   = ci0 >> 9;
  const float* src = Y + ((size_t)(b * 2048 + ci0)) * 1024 + l0;
#pragma unroll
  for (int i = 0; i < 16; ++i) {
    int idx = threadIdx.x + i * 256;
    int ci = idx >> 7, pp = idx & 127;
    t[ci][pp] = src[(size_t)ci * 1024 + pp];
  }
  __syncthreads();
  {
    int ci = threadIdx.x & 31, seg = threadIdx.x >> 5;
    float s = 0.f;
#pragma unroll
    for (int j = 0; j < 16; ++j) s += t[ci][seg * 16 + j];
    atomicAdd(&cavg[b * 2048 + ci0 + ci], s * (1.f / 1024.f));
  }
  int pp = threadIdx.x >> 1;
  int ch = (threadIdx.x & 1) * 16;
  _Float16 buf[16];
#pragma unroll
  for (int j = 0; j < 16; ++j) buf[j] = (_Float16)t[ch + j][pp];
  int pix = srcmap(r, l0 + pp);
  _Float16* dst = Ytg + ((size_t)(b * 1024) + pix) * 2048 + ci0 + ch;
  *(float4*)dst = *(const float4*)buf;
  *(float4*)(dst + 8) = *(const float4*)(buf + 8);
}

// ---------------- spatial-attn conv1 v5 (PROVEN): A and B staged in LDS, [40] pads ----------------
__global__ void __launch_bounds__(256, 2) k_samfma(const _Float16* __restrict__ Ytg,
                                                   const _Float16* __restrict__ Whg2,
                                                   float* __restrict__ cpart) {
  __shared__ __align__(16) _Float16 As[6][32][40];   // 15 KB, 16B-aligned stride, 2-way free
  __shared__ __align__(16) _Float16 Bs[9][64][40];   // 45 KB
  int L = blockIdx.x;
  int ks = L & 7;
  int rem = L >> 3;             // 0..63
  int b = rem >> 3, rg = rem & 7;
  int tid = threadIdx.x;
  int wid = tid >> 6, lane = tid & 63;
  int r = lane & 15, g = lane >> 4;
  const _Float16* Yb = Ytg + (size_t)b * (1024 * 2048);
  const half8 zero8 = {0, 0, 0, 0, 0, 0, 0, 0};

  int srow[3], scol[3], sci8[3], srcoff[3]; bool sok[3];
#pragma unroll
  for (int i = 0; i < 3; ++i) {
    int unit = tid + i * 256;
    srow[i] = unit >> 7; scol[i] = (unit >> 2) & 31; sci8[i] = unit & 3;
    int grow = rg * 4 - 1 + srow[i];
    sok[i] = ((unsigned)grow < 32u);
    srcoff[i] = ((sok[i] ? grow : 0) * 32 + scol[i]) * 2048 + sci8[i] * 8;
  }
  int bcol = tid >> 2, bci8 = tid & 3;
  int ci_base = ks * 256;

  for (int coh = 0; coh < 2; ++coh) {
    f4 acc[2][4];
#pragma unroll
    for (int mi = 0; mi < 2; ++mi)
#pragma unroll
      for (int ni = 0; ni < 4; ++ni) acc[mi][ni] = (f4){0.f, 0.f, 0.f, 0.f};

    half8 pa[3], pb[9];
#pragma unroll
    for (int i = 0; i < 3; ++i) {
      half8 v = *(const half8*)(Yb + srcoff[i] + ci_base);
      pa[i] = sok[i] ? v : zero8;
    }
#pragma unroll
    for (int j = 0; j < 9; ++j)
      pb[j] = *(const half8*)(Whg2 + (((size_t)(j * 64 + ks * 8) * 128) + coh * 64 + bcol) * 32 + bci8 * 8);

    for (int ch = 0; ch < 8; ++ch) {
      __syncthreads();
#pragma unroll
      for (int i = 0; i < 3; ++i)
        *(half8*)&As[srow[i]][scol[i]][sci8[i] * 8] = pa[i];
#pragma unroll
      for (int j = 0; j < 9; ++j)
        *(half8*)&Bs[j][bcol][bci8 * 8] = pb[j];
      if (ch < 7) {
        int ci0 = ci_base + (ch + 1) * 32;
#pragma unroll
        for (int i = 0; i < 3; ++i) {
          half8 v = *(const half8*)(Yb + srcoff[i] + ci0);
          pa[i] = sok[i] ? v : zero8;
        }
        int cic = ks * 8 + ch + 1;
#pragma unroll
        for (int j = 0; j < 9; ++j)
          pb[j] = *(const half8*)(Whg2 + (((size_t)(j * 64 + cic) * 128) + coh * 64 + bcol) * 32 + bci8 * 8);
      }
      __syncthreads();

#pragma unroll
      for (int tap = 0; tap < 9; ++tap) {
        const int dh = tap / 3 - 1, dw = tap % 3 - 1;
        int lrow = wid + dh + 1;
        half8 av[2], bv[4];
#pragma unroll
        for (int mi = 0; mi < 2; ++mi) {
          int lcol = mi * 16 + r + dw;
          bool ok = ((unsigned)lcol < 32u);
          half8 v = *(const half8*)&As[lrow][lcol & 31][g * 8];
          av[mi] = ok ? v : zero8;
        }
#pragma unroll
        for (int ni = 0; ni < 4; ++ni)
          bv[ni] = *(const half8*)&Bs[tap][ni * 16 + r][g * 8];
#pragma unroll
        for (int mi = 0; mi < 2; ++mi)
#pragma unroll
          for (int ni = 0; ni < 4; ++ni)
            acc[mi][ni] = __builtin_amdgcn_mfma_f32_16x16x32_f16(av[mi], bv[ni], acc[mi][ni], 0, 0, 0);
      }
    }

    float* cp = cpart + (size_t)ks * (8192 * 128);
    int basepix = b * 1024 + (rg * 4 + wid) * 32;
#pragma unroll
    for (int mi = 0; mi < 2; ++mi)
#pragma unroll
      for (int ni = 0; ni < 4; ++ni) {
        int co = coh * 64 + ni * 16 + r;
#pragma unroll
        for (int j = 0; j < 4; ++j)
          cp[(size_t)(basepix + mi * 16 + g * 4 + j) * 128 + co] = acc[mi][ni][j];
      }
    __syncthreads();
  }
}

// ---------------- reduce 8 partials + bias + relu + conv2 + softmax ----------------
__global__ void __launch_bounds__(256) k_saconv2f(const float* __restrict__ cpart,
                                                  const float* __restrict__ sab1,
                                                  const float* __restrict__ saw2,
                                                  const float* __restrict__ sab2,
                                                  float* __restrict__ swout) {
  int tid = threadIdx.x;
  int pixg = tid >> 3, cig = tid & 7;
  int p = blockIdx.x * 32 + pixg;
  int b = blockIdx.y;
  int pix = b * 1024 + p;
  const float* c0 = cpart + (size_t)pix * 128 + cig * 16;
  float a0 = 0.f, a1 = 0.f, a2 = 0.f, a3 = 0.f;
#pragma unroll
  for (int j4 = 0; j4 < 4; ++j4) {
    float sx = 0.f, sy = 0.f, sz = 0.f, sw_ = 0.f;
#pragma unroll
    for (int k = 0; k < 8; ++k) {
      float4 v = *(const float4*)(c0 + (size_t)k * 1048576 + j4 * 4);
      sx += v.x; sy += v.y; sz += v.z; sw_ += v.w;
    }
    int ci = cig * 16 + j4 * 4;
    float v0 = fmaxf(sx + sab1[ci],     0.f);
    float v1 = fmaxf(sy + sab1[ci + 1], 0.f);
    float v2 = fmaxf(sz + sab1[ci + 2], 0.f);
    float v3 = fmaxf(sw_ + sab1[ci + 3], 0.f);
    a0 = fmaf(v0, saw2[ci], fmaf(v1, saw2[ci+1], fmaf(v2, saw2[ci+2], fmaf(v3, saw2[ci+3], a0))));
    a1 = fmaf(v0, saw2[128+ci], fmaf(v1, saw2[128+ci+1], fmaf(v2, saw2[128+ci+2], fmaf(v3, saw2[128+ci+3], a1))));
    a2 = fmaf(v0, saw2[256+ci], fmaf(v1, saw2[256+ci+1], fmaf(v2, saw2[256+ci+2], fmaf(v3, saw2[256+ci+3], a2))));
    a3 = fmaf(v0, saw2[384+ci], fmaf(v1, saw2[384+ci+1], fmaf(v2, saw2[384+ci+2], fmaf(v3, saw2[384+ci+3], a3))));
  }
#pragma unroll
  for (int off = 4; off > 0; off >>= 1) {
    a0 += __shfl_down(a0, off, 8);
    a1 += __shfl_down(a1, off, 8);
    a2 += __shfl_down(a2, off, 8);
    a3 += __shfl_down(a3, off, 8);
  }
  if (cig == 0) {
    a0 += sab2[0]; a1 += sab2[1]; a2 += sab2[2]; a3 += sab2[3];
    float m = fmaxf(fmaxf(a0, a1), fmaxf(a2, a3));
    float e0 = __expf(a0 - m), e1 = __expf(a1 - m), e2 = __expf(a2 - m), e3 = __expf(a3 - m);
    float inv = 1.f / (e0 + e1 + e2 + e3);
    swout[(b * 4 + 0) * 1024 + p] = e0 * inv;
    swout[(b * 4 + 1) * 1024 + p] = e1 * inv;
    swout[(b * 4 + 2) * 1024 + p] = e2 * inv;
    swout[(b * 4 + 3) * 1024 + p] = e3 * inv;
  }
}

// ---------------- channel attention ----------------
__global__ void k_cw(const float* __restrict__ cavg, const float* __restrict__ caw1,
                     const float* __restrict__ caw2, float* __restrict__ cwout) {
  int b = blockIdx.x;
  int t = threadIdx.x;
  __shared__ float hid[32];
  __shared__ float vv[4];
  if (t < 32) {
    float a = 0.f;
    const float* cv = cavg + b * 2048;
    const float* wr = caw1 + t * 2048;
    for (int i = 0; i < 2048; ++i) a = fmaf(wr[i], cv[i], a);
    hid[t] = fmaxf(a, 0.f);
  }
  __syncthreads();
  if (t < 4) {
    float a = 0.f;
    for (int i = 0; i < 32; ++i) a = fmaf(caw2[t * 32 + i], hid[i], a);
    vv[t] = a;
  }
  __syncthreads();
  if (t < 4) {
    float m = fmaxf(fmaxf(vv[0], vv[1]), fmaxf(vv[2], vv[3]));
    float e = __expf(vv[t] - m);
    float s = __expf(vv[0] - m) + __expf(vv[1] - m) + __expf(vv[2] - m) + __expf(vv[3] - m);
    cwout[b * 4 + t] = e / s;
  }
}

// ---------------- catH: mixes from Ytg (fp16, un-rotated) -> fp16 pix-major concat ----------------
__global__ void __launch_bounds__(256) k_catH(const _Float16* __restrict__ Ytg,
                                              const float* __restrict__ swv,
                                              const float* __restrict__ cwv,
                                              _Float16* __restrict__ catO) {
  int p0 = blockIdx.x * 64, c0 = blockIdx.y * 64, b = blockIdx.z;
  int pp = threadIdx.x >> 2, cs = (threadIdx.x & 3) * 16;
  int pix = p0 + pp;
  const _Float16* src = Ytg + (size_t)(b * 1024 + pix) * 2048 + c0 + cs;
  float accS[16], accC[16];
#pragma unroll
  for (int j = 0; j < 16; ++j) { accS[j] = 0.f; accC[j] = 0.f; }
#pragma unroll
  for (int r = 0; r < 4; ++r) {
    half8 v0 = *(const half8*)(src + r * 512);
    half8 v1 = *(const half8*)(src + r * 512 + 8);
    float sw = swv[(size_t)(b * 4 + r) * 1024 + pix];
    float cw = cwv[b * 4 + r];
#pragma unroll
    for (int j = 0; j < 8; ++j) {
      float f0 = (float)v0[j], f1 = (float)v1[j];
      accS[j]     = fmaf(f0, sw, accS[j]);
      accS[j + 8] = fmaf(f1, sw, accS[j + 8]);
      accC[j]     = fmaf(f0, cw, accC[j]);
      accC[j + 8] = fmaf(f1, cw, accC[j + 8]);
    }
  }
  _Float16 os[16], oc[16];
#pragma unroll
  for (int j = 0; j < 16; ++j) { os[j] = (_Float16)accS[j]; oc[j] = (_Float16)accC[j]; }
  _Float16* dst = catO + ((size_t)(b * 1024) + pix) * 1024;
  *(half8*)(dst + c0 + cs)       = *(half8*)os;
  *(half8*)(dst + c0 + cs + 8)   = *(half8*)(os + 8);
  *(half8*)(dst + 512 + c0 + cs)     = *(half8*)oc;
  *(half8*)(dst + 512 + c0 + cs + 8) = *(half8*)(oc + 8);
}

// ---------------- gate 1x1 conv (1024->512) via MFMA + sigmoid fuse -> fusedH ----------------
__global__ void __launch_bounds__(256) k_gatemfma(const _Float16* __restrict__ catO,
                                                  const _Float16* __restrict__ gwH,
                                                  const float* __restrict__ gb,
                                                  _Float16* __restrict__ fusedH) {
  int wid = threadIdx.x >> 6, lane = threadIdx.x & 63;
  int r = lane & 15, g = lane >> 4;
  int p0 = blockIdx.x * 128 + (wid >> 1) * 64;
  int c0 = blockIdx.y * 128 + (wid & 1) * 64;
  int b  = blockIdx.z;
  const _Float16* Cb = catO + (size_t)b * (1024 * 1024);
  f4 acc[4][4];
#pragma unroll
  for (int mi = 0; mi < 4; ++mi)
#pragma unroll
    for (int ni = 0; ni < 4; ++ni) acc[mi][ni] = (f4){0.f, 0.f, 0.f, 0.f};
  for (int kk = 0; kk < 1024; kk += 32) {
    half8 av[4], bv[4];
#pragma unroll
    for (int mi = 0; mi < 4; ++mi)
      av[mi] = *(const half8*)(Cb + (size_t)(p0 + mi * 16 + r) * 1024 + kk + g * 8);
#pragma unroll
    for (int ni = 0; ni < 4; ++ni)
      bv[ni] = *(const half8*)(gwH + (size_t)(c0 + ni * 16 + r) * 1024 + kk + g * 8);
#pragma unroll
    for (int mi = 0; mi < 4; ++mi)
#pragma unroll
      for (int ni = 0; ni < 4; ++ni)
        acc[mi][ni] = __builtin_amdgcn_mfma_f32_16x16x32_f16(av[mi], bv[ni], acc[mi][ni], 0, 0, 0);
  }
#pragma unroll
  for (int ni = 0; ni < 4; ++ni) {
    int c = c0 + ni * 16 + r;
    float bias = gb[c];
#pragma unroll
    for (int mi = 0; mi < 4; ++mi)
#pragma unroll
      for (int j = 0; j < 4; ++j) {
        int pix = p0 + mi * 16 + g * 4 + j;
        const _Float16* rowp = Cb + (size_t)pix * 1024 + c;
        float sp = (float)rowp[0], ch = (float)rowp[512];
        float gt = sigmoidf_(acc[mi][ni][j] + bias);
        fusedH[((size_t)(b * 1024) + pix) * 512 + c] = (_Float16)(gt * sp + (1.f - gt) * ch);
      }
  }
}

// ---------------- out_proj (512->256) via MFMA + GELU ----------------
__global__ void __launch_bounds__(256) k_outprojmfma(const _Float16* __restrict__ fusedH,
                                                     const _Float16* __restrict__ opH,
                                                     float* __restrict__ out) {
  int wid = threadIdx.x >> 6, lane = threadIdx.x & 63;
  int r = lane & 15, g = lane >> 4;
  int m0 = blockIdx.x * 64;
  int n0 = blockIdx.y * 256 + wid * 64;
  int b  = blockIdx.z;
  f4 acc[4][4];
#pragma unroll
  for (int mi = 0; mi < 4; ++mi)
#pragma unroll
    for (int ni = 0; ni < 4; ++ni) acc[mi][ni] = (f4){0.f, 0.f, 0.f, 0.f};
  for (int kk = 0; kk < 512; kk += 32) {
    half8 av[4], bv[4];
#pragma unroll
    for (int mi = 0; mi < 4; ++mi)
      av[mi] = *(const half8*)(opH + (size_t)(m0 + mi * 16 + r) * 512 + kk + g * 8);
#pragma unroll
    for (int ni = 0; ni < 4; ++ni)
      bv[ni] = *(const half8*)(fusedH + ((size_t)(b * 1024) + n0 + ni * 16 + r) * 512 + kk + g * 8);
#pragma unroll
    for (int mi = 0; mi < 4; ++mi)
#pragma unroll
      for (int ni = 0; ni < 4; ++ni)
        acc[mi][ni] = __builtin_amdgcn_mfma_f32_16x16x32_f16(av[mi], bv[ni], acc[mi][ni], 0, 0, 0);
  }
#pragma unroll
  for (int mi = 0; mi < 4; ++mi)
#pragma unroll
    for (int ni = 0; ni < 4; ++ni) {
      int pix = n0 + ni * 16 + r;
#pragma unroll
      for (int j = 0; j < 4; ++j) {
        int co = m0 + mi * 16 + g * 4 + j;
        out[((size_t)(b * 256) + co) * 1024 + pix] = geluf(acc[mi][ni][j]);
      }
    }
}

extern "C" void kernel_launch(void* const* d_in, const int* in_sizes, int n_in,
                              void* d_out, int out_size, void* d_ws, size_t ws_size,
                              hipStream_t stream) {
  const float* x    = (const float*)d_in[0];
  const float* inw  = (const float*)d_in[1];
  const float* opw  = (const float*)d_in[2];
  const float* cxw  = (const float*)d_in[3];
  const float* cxb  = (const float*)d_in[4];
  const float* czw  = (const float*)d_in[5];
  const float* czb  = (const float*)d_in[6];
  const float* xpw  = (const float*)d_in[7];
  const float* dtw  = (const float*)d_in[8];
  const float* dtb  = (const float*)d_in[9];
  const float* alog = (const float*)d_in[10];
  const float* ds   = (const float*)d_in[11];
  const float* saw1 = (const float*)d_in[12];
  const float* sab1 = (const float*)d_in[13];
  const float* saw2 = (const float*)d_in[14];
  const float* sab2 = (const float*)d_in[15];
  const float* caw1 = (const float*)d_in[16];
  const float* caw2 = (const float*)d_in[17];
  const float* gw   = (const float*)d_in[18];
  const float* gb   = (const float*)d_in[19];

  float* ws = (float*)d_ws;
  float* xz   = ws + 0;          //  4,194,304  [alias: sp16 fp16 -> catO fp16]
  float* xseq = ws + 4194304;    //  8,388,608  [alias: Ytg fp16 -> fusedH fp16]
  float* xdT  = ws + 12582912;   //  1,572,864
  float* Y    = ws + 14155776;   // 16,777,216  [alias: xTh/xTl pre-conv] rotated; carries; Cpart
  float* spsum= ws + 30932992;   //    262,144
  float* swb  = ws + 31981568;   //     32,768
  float* cavg = ws + 32014336;   //     16,384
  float* cwb  = ws + 32030720;   //         32
  float* inWHL= ws + 32030752;   //    131,072 (inwH + inwL fp16)
  float* opHF = ws + 32161824;   //    131,072 (opH fp16)
  float* gwHF = ws + 32292896;   //    524,288 (gwH fp16)
  float* WhgF = ws + 32817184;   //  1,179,648 (Whg2 fp16)
  float* Cpart  = Y;             //  8,388,608 (8ks x 8192pix x 128co)
  _Float16* sp16   = (_Float16*)xz;      // 8,388,608 halves
  _Float16* Ytg    = (_Float16*)xseq;
  _Float16* catO   = (_Float16*)xz;      // after scanC consumed sp16
  _Float16* fusedH = (_Float16*)xseq;
  _Float16* Whg2 = (_Float16*)WhgF;
  _Float16* gwH = (_Float16*)gwHF;
  _Float16* opH = (_Float16*)opHF;
  _Float16* inwH = (_Float16*)inWHL;
  _Float16* inwL = (_Float16*)(inWHL + 65536);
  _Float16* xTh  = (_Float16*)Y;
  _Float16* xTl  = (_Float16*)(Y + 1048576);

  k_prep<<<12352, 256, 0, stream>>>(inw, gw, opw, saw1, inwH, inwL, gwH, opH, cavg, Whg2);
  k_xT<<<dim3(8, 8, 8), 256, 0, stream>>>(x, xTh, xTl);
  k_inprojmfma<<<dim3(4, 8, 8), 256, 0, stream>>>(xTh, xTl, inwH, inwL, xz);
  k_conv<<<dim3(256, 8), 256, 0, stream>>>(xz, cxw, cxb, czw, czb, xseq, Y);
  k_xdblT<<<dim3(32, 32), 256, 0, stream>>>(xseq, xpw, xdT);
  k_scanA<<<dim3(32, 32), 256, 0, stream>>>(xseq, xdT, dtw, dtb, alog, spsum, sp16, Y);
  k_scanB<<<512, 256, 0, stream>>>(spsum, alog, Y);
  k_scanC<<<dim3(32, 32), 256, 0, stream>>>(xseq, xdT, sp16, alog, ds, Y);
  k_ytr<<<dim3(8, 64, 8), 256, 0, stream>>>(Y, Ytg, cavg);
  k_cw<<<8, 64, 0, stream>>>(cavg, caw1, caw2, cwb);
  k_samfma<<<512, 256, 0, stream>>>(Ytg, Whg2, Cpart);
  k_saconv2f<<<dim3(32, 8), 256, 0, stream>>>(Cpart, sab1, saw2, sab2, swb);
  k_catH<<<dim3(16, 8, 8), 256, 0, stream>>>(Ytg, swb, cwb, catO);
  k_gatemfma<<<dim3(8, 4, 8), 256, 0, stream>>>(catO, gwH, gb, fusedH);
  k_outprojmfma<<<dim3(4, 4, 8), 256, 0, stream>>>(fusedH, opH, (float*)d_out);
}